// Round 4
// baseline (150.715 us; speedup 1.0000x reference)
//
#include <hip/hip_runtime.h>

// Problem constants (fixed by setup_inputs): B=8, C=64, NX=NY=512.
#define BATCH 8
#define CCH   64            // num_bev_features
#define NXC   512
#define NYC   512
#define SLOTS (NXC * NYC)   // 262144 slots per batch image
#define S4    (SLOTS / 4)   // 65536 float4-groups per (b,c) plane

typedef float f32x4 __attribute__((ext_vector_type(4)));

// Pass 0: init winner to -1 (runtime fillBufferAligned ran at 26 GB/s; ours ~1.4us).
__global__ void init_winner(int4* __restrict__ winner4) {
    int i = blockIdx.x * blockDim.x + threadIdx.x;   // exactly BATCH*SLOTS/4 threads
    winner4[i] = make_int4(-1, -1, -1, -1);
}

// Pass 1: last-write-wins winner per flat slot via atomicMax on pillar index.
// max is commutative -> deterministic; "largest i wins" == numpy assignment
// semantics (verified: absmax 0.0).
__global__ void winner_kernel(const int* __restrict__ coords,
                              int* __restrict__ winner, int n) {
    int i = blockIdx.x * blockDim.x + threadIdx.x;
    if (i >= n) return;
    int4 c4 = *reinterpret_cast<const int4*>(coords + (size_t)i * 4);
    int flat = c4.x * SLOTS + c4.y + c4.z * NXC + c4.w;  // b*nx*ny + z + y*nx + x
    atomicMax(&winner[flat], i);
}

// Pass 2: fused zero-fill + gather, R2 mapping (best so far: max occupancy,
// 4M threads, winner/feat re-reads L2-absorbed same-XCD).
// A/B vs R2: plain stores instead of __builtin_nontemporal_store — the
// harness's 6.8 TB/s fill kernels use plain stores; nt may bypass L2 write
// coalescing and cost write-stream efficiency.
__global__ void fill_gather2(const float* __restrict__ feat,
                             const int* __restrict__ winner,
                             float* __restrict__ out) {
    int e = blockIdx.x * blockDim.x + threadIdx.x;  // BATCH * (CCH/8) * S4 threads
    int p4 = e & (S4 - 1);          // slot-group within plane
    int cg = (e >> 16) & 7;         // channel-group (8 channels)
    int b  = e >> 19;               // batch
    const int c0 = cg * 8;

    int4 w4 = *reinterpret_cast<const int4*>(winner + (size_t)b * SLOTS + (size_t)p4 * 4);
    int w[4] = {w4.x, w4.y, w4.z, w4.w};

    float f[4][8];
    #pragma unroll
    for (int j = 0; j < 4; ++j) {
        if (w[j] >= 0) {
            const float* row = feat + (size_t)w[j] * CCH + c0;
            float4 lo = *reinterpret_cast<const float4*>(row);
            float4 hi = *reinterpret_cast<const float4*>(row + 4);
            f[j][0] = lo.x; f[j][1] = lo.y; f[j][2] = lo.z; f[j][3] = lo.w;
            f[j][4] = hi.x; f[j][5] = hi.y; f[j][6] = hi.z; f[j][7] = hi.w;
        } else {
            #pragma unroll
            for (int c = 0; c < 8; ++c) f[j][c] = 0.0f;
        }
    }

    size_t base = ((size_t)b * CCH + c0) * SLOTS + (size_t)p4 * 4;
    #pragma unroll
    for (int c = 0; c < 8; ++c) {
        f32x4 v = {f[0][c], f[1][c], f[2][c], f[3][c]};
        *reinterpret_cast<f32x4*>(out + base + (size_t)c * SLOTS) = v;
    }
}

extern "C" void kernel_launch(void* const* d_in, const int* in_sizes, int n_in,
                              void* d_out, int out_size, void* d_ws, size_t ws_size,
                              hipStream_t stream) {
    const float* feat   = (const float*)d_in[0];   // (N, 64) f32
    const int*   coords = (const int*)d_in[1];     // (N, 4)  i32
    float*       out    = (float*)d_out;           // (8, 64, 512, 512) f32
    int n = in_sizes[1] / 4;                       // N = 200000

    int* winner = (int*)d_ws;                      // 8 MiB: BATCH*SLOTS ints

    init_winner<<<(BATCH * SLOTS / 4) / 256, 256, 0, stream>>>((int4*)winner);
    winner_kernel<<<(n + 255) / 256, 256, 0, stream>>>(coords, winner, n);

    int total_threads = BATCH * (CCH / 8) * S4;    // 4,194,304
    fill_gather2<<<total_threads / 256, 256, 0, stream>>>(feat, winner, out);
}

// Round 6
// 111.447 us; speedup vs baseline: 1.3523x; 1.3523x over previous
//
#include <hip/hip_runtime.h>

// Problem constants (fixed by setup_inputs): B=8, C=64, NX=NY=512.
#define BATCH 8
#define CCH   64            // num_bev_features
#define NXC   512
#define NYC   512
#define SLOTS (NXC * NYC)   // 262144 slots per batch image
#define S4    (SLOTS / 4)   // 65536 float4-groups per (b,c) plane

typedef float f32x4 __attribute__((ext_vector_type(4)));
typedef int   i32x4 __attribute__((ext_vector_type(4)));  // nt builtins need ext_vector, not HIP_vector_type

// Pass 0: init winner to -1. Plain stores (NOT nt): winner is immediately
// re-read by scatter + gather, so we want it L2-resident.
__global__ void __launch_bounds__(256) init_winner(i32x4* __restrict__ winner4) {
    int i = blockIdx.x * blockDim.x + threadIdx.x;   // exactly BATCH*SLOTS/4 threads
    winner4[i] = i32x4{-1, -1, -1, -1};
}

// Pass 1: last-write-wins winner per flat slot via atomicMax on pillar index.
// max is commutative -> deterministic; "largest i wins" == numpy assignment
// semantics (verified: absmax 0.0 in R1-R4).
__global__ void __launch_bounds__(256) winner_kernel(const int* __restrict__ coords,
                                                     int* __restrict__ winner, int n) {
    int i = blockIdx.x * blockDim.x + threadIdx.x;
    if (i >= n) return;
    // coords has zero reuse -> nontemporal load keeps L2 for winner
    i32x4 c4 = __builtin_nontemporal_load(
        reinterpret_cast<const i32x4*>(coords + (size_t)i * 4));
    int flat = c4.x * SLOTS + c4.y + c4.z * NXC + c4.w;  // b*nx*ny + z + y*nx + x
    atomicMax(&winner[flat], i);
}

// Pass 2: fused zero-fill + gather — best-known config (R2: 111.0 us):
//   thread = (b, channel-group of 8, slot-group of 4); 4,194,304 threads;
//   max occupancy; winner/feat re-reads L2-absorbed (cg-sibling blocks are
//   256 apart -> same XCD since 256 % 8 == 0).
// NONTEMPORAL output stores are load-bearing: plain stores = +36% (R4 A/B) —
// the 537 MB write stream must bypass L2 to preserve winner/feat residency.
__global__ void __launch_bounds__(256) fill_gather2(const float* __restrict__ feat,
                                                    const int* __restrict__ winner,
                                                    float* __restrict__ out) {
    int e = blockIdx.x * blockDim.x + threadIdx.x;  // BATCH * (CCH/8) * S4 threads
    int p4 = e & (S4 - 1);          // slot-group within plane
    int cg = (e >> 16) & 7;         // channel-group (8 channels)
    int b  = e >> 19;               // batch
    const int c0 = cg * 8;

    int4 w4 = *reinterpret_cast<const int4*>(winner + (size_t)b * SLOTS + (size_t)p4 * 4);
    int w[4] = {w4.x, w4.y, w4.z, w4.w};

    float f[4][8];
    #pragma unroll
    for (int j = 0; j < 4; ++j) {
        if (w[j] >= 0) {
            const float* row = feat + (size_t)w[j] * CCH + c0;
            float4 lo = *reinterpret_cast<const float4*>(row);
            float4 hi = *reinterpret_cast<const float4*>(row + 4);
            f[j][0] = lo.x; f[j][1] = lo.y; f[j][2] = lo.z; f[j][3] = lo.w;
            f[j][4] = hi.x; f[j][5] = hi.y; f[j][6] = hi.z; f[j][7] = hi.w;
        } else {
            #pragma unroll
            for (int c = 0; c < 8; ++c) f[j][c] = 0.0f;
        }
    }

    size_t base = ((size_t)b * CCH + c0) * SLOTS + (size_t)p4 * 4;
    #pragma unroll
    for (int c = 0; c < 8; ++c) {
        f32x4 v = {f[0][c], f[1][c], f[2][c], f[3][c]};
        __builtin_nontemporal_store(v, reinterpret_cast<f32x4*>(out + base + (size_t)c * SLOTS));
    }
}

extern "C" void kernel_launch(void* const* d_in, const int* in_sizes, int n_in,
                              void* d_out, int out_size, void* d_ws, size_t ws_size,
                              hipStream_t stream) {
    const float* feat   = (const float*)d_in[0];   // (N, 64) f32
    const int*   coords = (const int*)d_in[1];     // (N, 4)  i32
    float*       out    = (float*)d_out;           // (8, 64, 512, 512) f32
    int n = in_sizes[1] / 4;                       // N = 200000

    int* winner = (int*)d_ws;                      // 8 MiB: BATCH*SLOTS ints

    init_winner<<<(BATCH * SLOTS / 4) / 256, 256, 0, stream>>>((i32x4*)winner);
    winner_kernel<<<(n + 255) / 256, 256, 0, stream>>>(coords, winner, n);

    int total_threads = BATCH * (CCH / 8) * S4;    // 4,194,304
    fill_gather2<<<total_threads / 256, 256, 0, stream>>>(feat, winner, out);
}